// Round 6
// baseline (1094.533 us; speedup 1.0000x reference)
//
#include <hip/hip_runtime.h>
#include <hip/hip_bf16.h>
#include <math.h>

#define NNODES 50000
#define NEDGES 800000
#define NGRAPH 512
#define FIN    256
#define H1     256
#define H2     256
#define H3     512
#define FPOUT  2048

// ---------------- utility kernels ----------------

__global__ __launch_bounds__(256) void zero_i32(int* p, int n) {
    int i = blockIdx.x * 256 + threadIdx.x;
    if (i < n) p[i] = 0;
}

__global__ __launch_bounds__(256) void count_deg(const int* __restrict__ ei, int* __restrict__ degi, int e_total) {
    int e = blockIdx.x * 256 + threadIdx.x;
    if (e >= e_total) return;
    int d = ei[e_total + e];
    atomicAdd(&degi[d], 1);
}

__global__ __launch_bounds__(256) void calc_dis(const int* __restrict__ degi, float* __restrict__ dis, int n) {
    int i = blockIdx.x * 256 + threadIdx.x;
    if (i < n) dis[i] = rsqrtf((float)(degi[i] + 1));   // +1 self loop
}

// inclusive scan per 256-chunk; offs[idx+1] = local inclusive, partials[b] = chunk sum
__global__ __launch_bounds__(256) void scanA(const int* __restrict__ degi, int* __restrict__ offs,
                                             int* __restrict__ partials, int n) {
    __shared__ int sm[256];
    int t = threadIdx.x, idx = blockIdx.x * 256 + t;
    int v = (idx < n) ? degi[idx] : 0;
    sm[t] = v; __syncthreads();
    for (int d = 1; d < 256; d <<= 1) {
        int add = (t >= d) ? sm[t - d] : 0;
        __syncthreads();
        sm[t] += add;
        __syncthreads();
    }
    if (idx < n) offs[idx + 1] = sm[t];
    if (t == 255) partials[blockIdx.x] = sm[255];
}

// exclusive scan of partials (nb <= 256), single block
__global__ __launch_bounds__(256) void scanB(int* __restrict__ partials, int nb) {
    __shared__ int sm[256];
    int t = threadIdx.x;
    int v = (t < nb) ? partials[t] : 0;
    sm[t] = v; __syncthreads();
    for (int d = 1; d < 256; d <<= 1) {
        int add = (t >= d) ? sm[t - d] : 0;
        __syncthreads();
        sm[t] += add;
        __syncthreads();
    }
    if (t < nb) partials[t] = sm[t] - v;   // exclusive
}

__global__ __launch_bounds__(256) void scanC(int* __restrict__ offs, const int* __restrict__ partials, int n) {
    int idx = blockIdx.x * 256 + threadIdx.x;
    if (idx < n) offs[idx + 1] += partials[blockIdx.x];
    if (idx == 0) offs[0] = 0;
}

__global__ __launch_bounds__(256) void copy_i32(const int* __restrict__ a, int* __restrict__ b, int n) {
    int i = blockIdx.x * 256 + threadIdx.x;
    if (i < n) b[i] = a[i];
}

__global__ __launch_bounds__(256) void fill_csr(const int* __restrict__ ei, const float* __restrict__ dis,
                                                int* __restrict__ curs, int* __restrict__ csr_src,
                                                float* __restrict__ csr_w, int e_total) {
    int e = blockIdx.x * 256 + threadIdx.x;
    if (e >= e_total) return;
    int s = ei[e];
    int d = ei[e_total + e];
    int pos = atomicAdd(&curs[d], 1);
    csr_src[pos] = s;
    csr_w[pos] = dis[s] * dis[d];
}

// ---------------- SGEMM 64x64 (kept for the small head GEMM) ----------------
__global__ __launch_bounds__(256) void sgemm(const float* __restrict__ A, const float* __restrict__ B,
                                             float* __restrict__ C, const float* __restrict__ bias,
                                             int M, int Nn, int K, int do_relu) {
    __shared__ float As[16][68];
    __shared__ float Bs[16][68];
    int tid = threadIdx.x;
    int tx = tid & 15, ty = tid >> 4;
    int row0 = blockIdx.y * 64, col0 = blockIdx.x * 64;
    int arow = tid >> 2, ac4 = (tid & 3) * 4;
    int brow = tid >> 4, bc4 = (tid & 15) * 4;
    float c[4][4] = {};
    for (int k0 = 0; k0 < K; k0 += 16) {
        float4 av = make_float4(0.f, 0.f, 0.f, 0.f);
        if (row0 + arow < M)
            av = *(const float4*)(A + (size_t)(row0 + arow) * K + k0 + ac4);
        As[ac4 + 0][arow] = av.x;
        As[ac4 + 1][arow] = av.y;
        As[ac4 + 2][arow] = av.z;
        As[ac4 + 3][arow] = av.w;
        float4 bv = *(const float4*)(B + (size_t)(k0 + brow) * Nn + col0 + bc4);
        *(float4*)&Bs[brow][bc4] = bv;
        __syncthreads();
        #pragma unroll
        for (int kk = 0; kk < 16; ++kk) {
            float4 a = *(float4*)&As[kk][ty * 4];
            float4 b = *(float4*)&Bs[kk][tx * 4];
            c[0][0] += a.x * b.x; c[0][1] += a.x * b.y; c[0][2] += a.x * b.z; c[0][3] += a.x * b.w;
            c[1][0] += a.y * b.x; c[1][1] += a.y * b.y; c[1][2] += a.y * b.z; c[1][3] += a.y * b.w;
            c[2][0] += a.z * b.x; c[2][1] += a.z * b.y; c[2][2] += a.z * b.z; c[2][3] += a.z * b.w;
            c[3][0] += a.w * b.x; c[3][1] += a.w * b.y; c[3][2] += a.w * b.z; c[3][3] += a.w * b.w;
        }
        __syncthreads();
    }
    #pragma unroll
    for (int i = 0; i < 4; ++i) {
        int row = row0 + ty * 4 + i;
        if (row >= M) continue;
        #pragma unroll
        for (int j = 0; j < 4; ++j) {
            int col = col0 + tx * 4 + j;
            float v = c[i][j];
            if (bias) v += bias[col];
            if (do_relu) v = v > 0.f ? v : 0.f;
            C[(size_t)row * Nn + col] = v;
        }
    }
}

// ---------------- SGEMM 128x128, 8x8 microtile (layer GEMMs) ----------------
// Requires Nn % 128 == 0, K % 16 == 0. M-guard on loads/stores.
__global__ __launch_bounds__(256) void sgemm128(const float* __restrict__ A, const float* __restrict__ B,
                                                float* __restrict__ C, const float* __restrict__ bias,
                                                int M, int Nn, int K, int do_relu) {
    __shared__ float As[16][132];   // [k][m], +4 pad
    __shared__ float Bs[16][132];   // [k][n], +4 pad
    int tid = threadIdx.x;
    int tx = tid & 15, ty = tid >> 4;
    int row0 = blockIdx.y * 128, col0 = blockIdx.x * 128;
    // A staging: thread t loads row ar = t>>1, k-offset (t&1)*8 .. +8 (two float4)
    int ar  = tid >> 1, ak = (tid & 1) * 8;
    // B staging: thread t loads k-row t>>4, cols (t&15)*8 .. +8 (two float4)
    int br  = tid >> 4, bc = (tid & 15) * 8;
    float acc[8][8] = {};
    for (int k0 = 0; k0 < K; k0 += 16) {
        float4 a0 = make_float4(0.f, 0.f, 0.f, 0.f), a1 = a0;
        if (row0 + ar < M) {
            const float* ap = A + (size_t)(row0 + ar) * K + k0 + ak;
            a0 = *(const float4*)ap;
            a1 = *(const float4*)(ap + 4);
        }
        As[ak + 0][ar] = a0.x; As[ak + 1][ar] = a0.y; As[ak + 2][ar] = a0.z; As[ak + 3][ar] = a0.w;
        As[ak + 4][ar] = a1.x; As[ak + 5][ar] = a1.y; As[ak + 6][ar] = a1.z; As[ak + 7][ar] = a1.w;
        const float* bp = B + (size_t)(k0 + br) * Nn + col0 + bc;
        *(float4*)&Bs[br][bc]     = *(const float4*)bp;
        *(float4*)&Bs[br][bc + 4] = *(const float4*)(bp + 4);
        __syncthreads();
        #pragma unroll
        for (int kk = 0; kk < 16; ++kk) {
            float4 av0 = *(float4*)&As[kk][ty * 8];
            float4 av1 = *(float4*)&As[kk][ty * 8 + 4];
            float4 bv0 = *(float4*)&Bs[kk][tx * 8];
            float4 bv1 = *(float4*)&Bs[kk][tx * 8 + 4];
            float a[8] = {av0.x, av0.y, av0.z, av0.w, av1.x, av1.y, av1.z, av1.w};
            float b[8] = {bv0.x, bv0.y, bv0.z, bv0.w, bv1.x, bv1.y, bv1.z, bv1.w};
            #pragma unroll
            for (int i = 0; i < 8; ++i)
                #pragma unroll
                for (int j = 0; j < 8; ++j)
                    acc[i][j] += a[i] * b[j];
        }
        __syncthreads();
    }
    #pragma unroll
    for (int i = 0; i < 8; ++i) {
        int row = row0 + ty * 8 + i;
        if (row >= M) continue;
        float* cp = C + (size_t)row * Nn + col0 + tx * 8;
        float4 o0, o1;
        o0.x = acc[i][0]; o0.y = acc[i][1]; o0.z = acc[i][2]; o0.w = acc[i][3];
        o1.x = acc[i][4]; o1.y = acc[i][5]; o1.z = acc[i][6]; o1.w = acc[i][7];
        if (bias) {
            const float* bb = bias + col0 + tx * 8;
            o0.x += bb[0]; o0.y += bb[1]; o0.z += bb[2]; o0.w += bb[3];
            o1.x += bb[4]; o1.y += bb[5]; o1.z += bb[6]; o1.w += bb[7];
        }
        if (do_relu) {
            o0.x = o0.x > 0.f ? o0.x : 0.f; o0.y = o0.y > 0.f ? o0.y : 0.f;
            o0.z = o0.z > 0.f ? o0.z : 0.f; o0.w = o0.w > 0.f ? o0.w : 0.f;
            o1.x = o1.x > 0.f ? o1.x : 0.f; o1.y = o1.y > 0.f ? o1.y : 0.f;
            o1.z = o1.z > 0.f ? o1.z : 0.f; o1.w = o1.w > 0.f ? o1.w : 0.f;
        }
        *(float4*)cp = o0;
        *(float4*)(cp + 4) = o1;
    }
}

// ---------------- aggregation: one wave per node, F=256, no bias/relu ----------------
// y[v] = sum_{s->v} x[s]*w + x[v]*dis[v]^2   (agg-first reorder: A@(xW) == (A@x)W)
__global__ __launch_bounds__(256) void agg256(const float* __restrict__ x, float* __restrict__ y,
                                              const float* __restrict__ dis,
                                              const int* __restrict__ offs, const int* __restrict__ csr_src,
                                              const float* __restrict__ csr_w) {
    constexpr int F = 256;
    constexpr int UNROLL = 8;
    int wave = threadIdx.x >> 6;
    int lane = threadIdx.x & 63;
    int v = __builtin_amdgcn_readfirstlane(blockIdx.x * 4 + wave);
    if (v >= NNODES) return;
    int beg = __builtin_amdgcn_readfirstlane(offs[v]);
    int end = __builtin_amdgcn_readfirstlane(offs[v + 1]);
    float dv = dis[v];
    float selfw = dv * dv;

    const float4* xv = (const float4*)(x + (size_t)v * F);
    float4 a = xv[lane];
    float4 acc = make_float4(a.x * selfw, a.y * selfw, a.z * selfw, a.w * selfw);

    int i = beg;
    for (; i + UNROLL <= end; i += UNROLL) {
        int   s[UNROLL];
        float w[UNROLL];
        #pragma unroll
        for (int u = 0; u < UNROLL; ++u) { s[u] = csr_src[i + u]; w[u] = csr_w[i + u]; }
        float4 g[UNROLL];
        #pragma unroll
        for (int u = 0; u < UNROLL; ++u)
            g[u] = ((const float4*)(x + (size_t)s[u] * F))[lane];
        #pragma unroll
        for (int u = 0; u < UNROLL; ++u) {
            acc.x += g[u].x * w[u]; acc.y += g[u].y * w[u];
            acc.z += g[u].z * w[u]; acc.w += g[u].w * w[u];
        }
    }
    for (; i + 2 <= end; i += 2) {
        int s0 = csr_src[i], s1 = csr_src[i + 1];
        float w0 = csr_w[i], w1 = csr_w[i + 1];
        float4 x0 = ((const float4*)(x + (size_t)s0 * F))[lane];
        float4 x1 = ((const float4*)(x + (size_t)s1 * F))[lane];
        acc.x += x0.x * w0 + x1.x * w1; acc.y += x0.y * w0 + x1.y * w1;
        acc.z += x0.z * w0 + x1.z * w1; acc.w += x0.w * w0 + x1.w * w1;
    }
    if (i < end) {
        int s0 = csr_src[i];
        float w0 = csr_w[i];
        float4 x0 = ((const float4*)(x + (size_t)s0 * F))[lane];
        acc.x += x0.x * w0; acc.y += x0.y * w0; acc.z += x0.z * w0; acc.w += x0.w * w0;
    }

    ((float4*)(y + (size_t)v * F))[lane] = acc;
}

// ---------------- gate: wgate[n] = sigmoid(x[n,:512] . pw + pb) ----------------
__global__ __launch_bounds__(256) void gate(const float* __restrict__ x, const float* __restrict__ pw,
                                            const float* __restrict__ pb, float* __restrict__ wgate, int n) {
    int wid = (blockIdx.x * 256 + threadIdx.x) >> 6;
    int lane = threadIdx.x & 63;
    if (wid >= n) return;
    const float4* xr = (const float4*)(x + (size_t)wid * 512);
    const float4* pwv = (const float4*)pw;
    float4 a = xr[lane], b = pwv[lane];
    float4 a1 = xr[lane + 64], b1 = pwv[lane + 64];
    float acc = a.x * b.x + a.y * b.y + a.z * b.z + a.w * b.w
              + a1.x * b1.x + a1.y * b1.y + a1.z * b1.z + a1.w * b1.w;
    #pragma unroll
    for (int off = 32; off; off >>= 1) acc += __shfl_down(acc, off, 64);
    if (lane == 0) wgate[wid] = 1.f / (1.f + expf(-(acc + pb[0])));
}

// ---------------- pool: pooled[g] = [weighted_sum(512) | max(512)] ----------------
__global__ __launch_bounds__(256) void pool(const float* __restrict__ x, const float* __restrict__ wg,
                                            const int* __restrict__ batch, float* __restrict__ pooled, int n) {
    int g = blockIdx.x;
    int t = threadIdx.x;
    int lo = 0, hi = n;
    while (lo < hi) { int mid = (lo + hi) >> 1; if (batch[mid] < g) lo = mid + 1; else hi = mid; }
    int start = lo;
    hi = n;
    while (lo < hi) { int mid = (lo + hi) >> 1; if (batch[mid] < g + 1) lo = mid + 1; else hi = mid; }
    int end = lo;
    float s0 = 0.f, s1 = 0.f, m0 = -INFINITY, m1 = -INFINITY;
    for (int nn = start; nn < end; ++nn) {
        float wn = wg[nn];
        const float* xr = x + (size_t)nn * 512;
        float v0 = xr[t], v1 = xr[t + 256];
        s0 += v0 * wn; s1 += v1 * wn;
        m0 = fmaxf(m0, v0); m1 = fmaxf(m1, v1);
    }
    if (start >= end) { m0 = 0.f; m1 = 0.f; }
    float* pg = pooled + (size_t)g * 1024;
    pg[t] = s0; pg[t + 256] = s1;
    pg[512 + t] = m0; pg[768 + t] = m1;
}

// ---------------- launch ----------------

extern "C" void kernel_launch(void* const* d_in, const int* in_sizes, int n_in,
                              void* d_out, int out_size, void* d_ws, size_t ws_size,
                              hipStream_t stream) {
    const float* x0    = (const float*)d_in[0];
    const int*   ei    = (const int*)d_in[1];
    const int*   batch = (const int*)d_in[2];
    const float* W1 = (const float*)d_in[3];
    const float* b1 = (const float*)d_in[4];
    const float* W2 = (const float*)d_in[5];
    const float* b2 = (const float*)d_in[6];
    const float* W3 = (const float*)d_in[7];
    const float* b3 = (const float*)d_in[8];
    const float* pw = (const float*)d_in[9];
    const float* pb = (const float*)d_in[10];
    const float* Wo = (const float*)d_in[11];
    const float* bo = (const float*)d_in[12];
    float* out = (float*)d_out;

    // workspace layout (4B words, each region 16B-aligned)
    float* ws = (float*)d_ws;
    size_t off = 0;
    float* bufA = ws + off; off += (size_t)NNODES * 512;   // agg outputs (256-wide)
    float* bufB = ws + off; off += (size_t)NNODES * 512;   // layer outputs
    float* dis  = ws + off; off += NNODES;
    int*   degi = (int*)(ws + off); off += NNODES;
    int*   offs = (int*)(ws + off); off += (NNODES + 4);
    int*   curs = (int*)(ws + off); off += NNODES;
    int*   csr_src = (int*)(ws + off); off += NEDGES;
    float* csr_w   = ws + off; off += NEDGES;
    float* wgate   = ws + off; off += NNODES;
    float* pooled  = ws + off; off += (size_t)NGRAPH * 1024;
    int*   partials = (int*)(ws + off); off += 256;

    const int NB_N = (NNODES + 255) / 256;   // 196
    const int NB_E = (NEDGES + 255) / 256;
    const int NB_W = (NNODES + 3) / 4;       // wave per node (12500)
    const int MB128 = (NNODES + 127) / 128;  // 391

    // CSR build
    zero_i32<<<NB_N, 256, 0, stream>>>(degi, NNODES);
    count_deg<<<NB_E, 256, 0, stream>>>(ei, degi, NEDGES);
    calc_dis<<<NB_N, 256, 0, stream>>>(degi, dis, NNODES);
    scanA<<<NB_N, 256, 0, stream>>>(degi, offs, partials, NNODES);
    scanB<<<1, 256, 0, stream>>>(partials, NB_N);
    scanC<<<NB_N, 256, 0, stream>>>(offs, partials, NNODES);
    copy_i32<<<NB_N, 256, 0, stream>>>(offs, curs, NNODES);
    fill_csr<<<NB_E, 256, 0, stream>>>(ei, dis, curs, csr_src, csr_w, NEDGES);

    // layer 1: y = A_norm @ x0 ; x1 = relu(y @ W1 + b1)
    agg256<<<NB_W, 256, 0, stream>>>(x0, bufA, dis, offs, csr_src, csr_w);
    {
        dim3 grid(H1 / 128, MB128);
        sgemm128<<<grid, 256, 0, stream>>>(bufA, W1, bufB, b1, NNODES, H1, FIN, 1);
    }
    // layer 2
    agg256<<<NB_W, 256, 0, stream>>>(bufB, bufA, dis, offs, csr_src, csr_w);
    {
        dim3 grid(H2 / 128, MB128);
        sgemm128<<<grid, 256, 0, stream>>>(bufA, W2, bufB, b2, NNODES, H2, H1, 1);
    }
    // layer 3: agg on 256-wide x2, GEMM 256->512
    agg256<<<NB_W, 256, 0, stream>>>(bufB, bufA, dis, offs, csr_src, csr_w);
    {
        dim3 grid(H3 / 128, MB128);
        sgemm128<<<grid, 256, 0, stream>>>(bufA, W3, bufB, b3, NNODES, H3, H2, 1);
    }
    // gate + pool
    gate<<<(NNODES * 64 + 255) / 256, 256, 0, stream>>>(bufB, pw, pb, wgate, NNODES);
    pool<<<NGRAPH, 256, 0, stream>>>(bufB, wgate, batch, pooled, NNODES);
    // head: out = relu(pooled @ Wo + bo)  (M=512 -> keep 64x64 tiling for grid size)
    {
        dim3 grid(FPOUT / 64, NGRAPH / 64);
        sgemm<<<grid, 256, 0, stream>>>(pooled, Wo, out, bo, NGRAPH, FPOUT, 2 * H3, 1);
    }
}

// Round 7
// 866.037 us; speedup vs baseline: 1.2638x; 1.2638x over previous
//
#include <hip/hip_runtime.h>
#include <hip/hip_bf16.h>
#include <math.h>

#define NNODES 50000
#define NEDGES 800000
#define NGRAPH 512
#define FIN    256
#define H1     256
#define H2     256
#define H3     512
#define FPOUT  2048

typedef __attribute__((ext_vector_type(8))) short short8;
typedef __attribute__((ext_vector_type(4))) float floatx4;

// bf16 round-to-nearest-even of a float, returned as raw bits
__device__ inline ushort bf16_rne(float x) {
    unsigned u = __float_as_uint(x);
    u = (u + 0x7FFFu + ((u >> 16) & 1u)) >> 16;
    return (ushort)u;
}
// split a = hi + lo, hi = truncate-to-bf16 (exact float), lo = bf16_rne(residual)
__device__ inline void split2(float a, ushort& h, ushort& l) {
    unsigned u = __float_as_uint(a);
    unsigned hb = u & 0xFFFF0000u;
    h = (ushort)(hb >> 16);
    l = bf16_rne(a - __uint_as_float(hb));
}

// ---------------- utility kernels ----------------

__global__ __launch_bounds__(256) void zero_i32(int* p, int n) {
    int i = blockIdx.x * 256 + threadIdx.x;
    if (i < n) p[i] = 0;
}

__global__ __launch_bounds__(256) void count_deg(const int* __restrict__ ei, int* __restrict__ degi, int e_total) {
    int e = blockIdx.x * 256 + threadIdx.x;
    if (e >= e_total) return;
    int d = ei[e_total + e];
    atomicAdd(&degi[d], 1);
}

__global__ __launch_bounds__(256) void calc_dis(const int* __restrict__ degi, float* __restrict__ dis, int n) {
    int i = blockIdx.x * 256 + threadIdx.x;
    if (i < n) dis[i] = rsqrtf((float)(degi[i] + 1));   // +1 self loop
}

__global__ __launch_bounds__(256) void scanA(const int* __restrict__ degi, int* __restrict__ offs,
                                             int* __restrict__ partials, int n) {
    __shared__ int sm[256];
    int t = threadIdx.x, idx = blockIdx.x * 256 + t;
    int v = (idx < n) ? degi[idx] : 0;
    sm[t] = v; __syncthreads();
    for (int d = 1; d < 256; d <<= 1) {
        int add = (t >= d) ? sm[t - d] : 0;
        __syncthreads();
        sm[t] += add;
        __syncthreads();
    }
    if (idx < n) offs[idx + 1] = sm[t];
    if (t == 255) partials[blockIdx.x] = sm[255];
}

__global__ __launch_bounds__(256) void scanB(int* __restrict__ partials, int nb) {
    __shared__ int sm[256];
    int t = threadIdx.x;
    int v = (t < nb) ? partials[t] : 0;
    sm[t] = v; __syncthreads();
    for (int d = 1; d < 256; d <<= 1) {
        int add = (t >= d) ? sm[t - d] : 0;
        __syncthreads();
        sm[t] += add;
        __syncthreads();
    }
    if (t < nb) partials[t] = sm[t] - v;   // exclusive
}

__global__ __launch_bounds__(256) void scanC(int* __restrict__ offs, const int* __restrict__ partials, int n) {
    int idx = blockIdx.x * 256 + threadIdx.x;
    if (idx < n) offs[idx + 1] += partials[blockIdx.x];
    if (idx == 0) offs[0] = 0;
}

__global__ __launch_bounds__(256) void copy_i32(const int* __restrict__ a, int* __restrict__ b, int n) {
    int i = blockIdx.x * 256 + threadIdx.x;
    if (i < n) b[i] = a[i];
}

__global__ __launch_bounds__(256) void fill_csr(const int* __restrict__ ei, const float* __restrict__ dis,
                                                int* __restrict__ curs, int* __restrict__ csr_src,
                                                float* __restrict__ csr_w, int e_total) {
    int e = blockIdx.x * 256 + threadIdx.x;
    if (e >= e_total) return;
    int s = ei[e];
    int d = ei[e_total + e];
    int pos = atomicAdd(&curs[d], 1);
    csr_src[pos] = s;
    csr_w[pos] = dis[s] * dis[d];
}

// W[K][N] fp32 -> Wt_hi[N][K], Wt_lo[N][K] bf16 bits (transpose + split)
__global__ __launch_bounds__(256) void wsplit(const float* __restrict__ W, ushort* __restrict__ hi,
                                              ushort* __restrict__ lo, int K, int N) {
    int idx = blockIdx.x * 256 + threadIdx.x;
    if (idx >= N * K) return;
    int n = idx / K, k = idx - n * K;
    float a = W[(size_t)k * N + n];
    ushort h, l; split2(a, h, l);
    hi[idx] = h; lo[idx] = l;
}

// ---------------- SGEMM 64x64 fp32 (head GEMM only) ----------------
__global__ __launch_bounds__(256) void sgemm(const float* __restrict__ A, const float* __restrict__ B,
                                             float* __restrict__ C, const float* __restrict__ bias,
                                             int M, int Nn, int K, int do_relu) {
    __shared__ float As[16][68];
    __shared__ float Bs[16][68];
    int tid = threadIdx.x;
    int tx = tid & 15, ty = tid >> 4;
    int row0 = blockIdx.y * 64, col0 = blockIdx.x * 64;
    int arow = tid >> 2, ac4 = (tid & 3) * 4;
    int brow = tid >> 4, bc4 = (tid & 15) * 4;
    float c[4][4] = {};
    for (int k0 = 0; k0 < K; k0 += 16) {
        float4 av = make_float4(0.f, 0.f, 0.f, 0.f);
        if (row0 + arow < M)
            av = *(const float4*)(A + (size_t)(row0 + arow) * K + k0 + ac4);
        As[ac4 + 0][arow] = av.x;
        As[ac4 + 1][arow] = av.y;
        As[ac4 + 2][arow] = av.z;
        As[ac4 + 3][arow] = av.w;
        float4 bv = *(const float4*)(B + (size_t)(k0 + brow) * Nn + col0 + bc4);
        *(float4*)&Bs[brow][bc4] = bv;
        __syncthreads();
        #pragma unroll
        for (int kk = 0; kk < 16; ++kk) {
            float4 a = *(float4*)&As[kk][ty * 4];
            float4 b = *(float4*)&Bs[kk][tx * 4];
            c[0][0] += a.x * b.x; c[0][1] += a.x * b.y; c[0][2] += a.x * b.z; c[0][3] += a.x * b.w;
            c[1][0] += a.y * b.x; c[1][1] += a.y * b.y; c[1][2] += a.y * b.z; c[1][3] += a.y * b.w;
            c[2][0] += a.z * b.x; c[2][1] += a.z * b.y; c[2][2] += a.z * b.z; c[2][3] += a.z * b.w;
            c[3][0] += a.w * b.x; c[3][1] += a.w * b.y; c[3][2] += a.w * b.z; c[3][3] += a.w * b.w;
        }
        __syncthreads();
    }
    #pragma unroll
    for (int i = 0; i < 4; ++i) {
        int row = row0 + ty * 4 + i;
        if (row >= M) continue;
        #pragma unroll
        for (int j = 0; j < 4; ++j) {
            int col = col0 + tx * 4 + j;
            float v = c[i][j];
            if (bias) v += bias[col];
            if (do_relu) v = v > 0.f ? v : 0.f;
            C[(size_t)row * Nn + col] = v;
        }
    }
}

// ---------------- MFMA split-bf16 GEMM: C = (Ahi+Alo)(Bhi+Blo)^T approx ----------------
// A: [M][K] bf16 bits (hi/lo), B: [N][K] bf16 bits (transposed weights, hi/lo).
// C[M][N] fp32 = relu(A.B^T + bias). 128x128 tile, 4 waves, wave = 64x64 via
// 4x4 grid of mfma_f32_16x16x32_bf16. 3-term: hi.hi + hi.lo + lo.hi.
// Fragment layouts (m89-verified): A-op A[m=lane&15][k=quad*8+j];
// B-op B[k=quad*8+j][n=lane&15]; C/D col=lane&15, row=quad*4+reg.
#define LSTR 40   // LDS row stride in ushort (32 data + 8 pad)
__global__ __launch_bounds__(256) void gemm_hl(const ushort* __restrict__ Ahi, const ushort* __restrict__ Alo,
                                               const ushort* __restrict__ Bhi, const ushort* __restrict__ Blo,
                                               float* __restrict__ C, const float* __restrict__ bias,
                                               int M, int N, int K, int do_relu) {
    __shared__ ushort lsAh[128 * LSTR];
    __shared__ ushort lsAl[128 * LSTR];
    __shared__ ushort lsBh[128 * LSTR];
    __shared__ ushort lsBl[128 * LSTR];
    int tid = threadIdx.x;
    int w = tid >> 6, lane = tid & 63;
    int quad = lane >> 4, lr = lane & 15;
    int wm = w & 1, wn = w >> 1;
    int row0 = blockIdx.y * 128, col0 = blockIdx.x * 128;

    floatx4 acc[4][4];
    #pragma unroll
    for (int i = 0; i < 4; ++i)
        #pragma unroll
        for (int j = 0; j < 4; ++j)
            acc[i][j] = (floatx4){0.f, 0.f, 0.f, 0.f};

    const short8 zer = {0, 0, 0, 0, 0, 0, 0, 0};
    int srow = tid >> 2;           // 0..63 (chunk adds +64)
    int skk  = (tid & 3) * 8;      // k offset within 32

    for (int k0 = 0; k0 < K; k0 += 32) {
        #pragma unroll
        for (int c = 0; c < 2; ++c) {
            int row = c * 64 + srow;
            size_t aoff = (size_t)(row0 + row) * K + k0 + skk;
            bool mok = (row0 + row) < M;
            short8 ah = mok ? *(const short8*)(Ahi + aoff) : zer;
            short8 al = mok ? *(const short8*)(Alo + aoff) : zer;
            size_t boff = (size_t)(col0 + row) * K + k0 + skk;
            short8 bh = *(const short8*)(Bhi + boff);
            short8 bl = *(const short8*)(Blo + boff);
            int lo = row * LSTR + skk;
            *(short8*)(lsAh + lo) = ah;
            *(short8*)(lsAl + lo) = al;
            *(short8*)(lsBh + lo) = bh;
            *(short8*)(lsBl + lo) = bl;
        }
        __syncthreads();
        short8 afh[4], afl[4];
        #pragma unroll
        for (int mt = 0; mt < 4; ++mt) {
            int ao = (wm * 64 + mt * 16 + lr) * LSTR + quad * 8;
            afh[mt] = *(const short8*)(lsAh + ao);
            afl[mt] = *(const short8*)(lsAl + ao);
        }
        #pragma unroll
        for (int nt = 0; nt < 4; ++nt) {
            int bo = (wn * 64 + nt * 16 + lr) * LSTR + quad * 8;
            short8 bfh = *(const short8*)(lsBh + bo);
            short8 bfl = *(const short8*)(lsBl + bo);
            #pragma unroll
            for (int mt = 0; mt < 4; ++mt) {
                acc[mt][nt] = __builtin_amdgcn_mfma_f32_16x16x32_bf16(afh[mt], bfh, acc[mt][nt], 0, 0, 0);
                acc[mt][nt] = __builtin_amdgcn_mfma_f32_16x16x32_bf16(afh[mt], bfl, acc[mt][nt], 0, 0, 0);
                acc[mt][nt] = __builtin_amdgcn_mfma_f32_16x16x32_bf16(afl[mt], bfh, acc[mt][nt], 0, 0, 0);
            }
        }
        __syncthreads();
    }

    #pragma unroll
    for (int mt = 0; mt < 4; ++mt) {
        #pragma unroll
        for (int r = 0; r < 4; ++r) {
            int row = row0 + wm * 64 + mt * 16 + quad * 4 + r;
            if (row >= M) continue;
            #pragma unroll
            for (int nt = 0; nt < 4; ++nt) {
                int col = col0 + wn * 64 + nt * 16 + lr;
                float v = acc[mt][nt][r] + bias[col];
                if (do_relu) v = v > 0.f ? v : 0.f;
                C[(size_t)row * N + col] = v;
            }
        }
    }
}

// ---------------- aggregation: wave per node, F=256, emits bf16 hi/lo ----------------
// y[v] = sum_{s->v} x[s]*w + x[v]*dis[v]^2   (agg-first reorder: A@(xW) == (A@x)W)
__global__ __launch_bounds__(256) void agg256hl(const float* __restrict__ x, ushort* __restrict__ yhi,
                                                ushort* __restrict__ ylo, const float* __restrict__ dis,
                                                const int* __restrict__ offs, const int* __restrict__ csr_src,
                                                const float* __restrict__ csr_w) {
    constexpr int F = 256;
    constexpr int UNROLL = 8;
    int wave = threadIdx.x >> 6;
    int lane = threadIdx.x & 63;
    int v = __builtin_amdgcn_readfirstlane(blockIdx.x * 4 + wave);
    if (v >= NNODES) return;
    int beg = __builtin_amdgcn_readfirstlane(offs[v]);
    int end = __builtin_amdgcn_readfirstlane(offs[v + 1]);
    float dv = dis[v];
    float selfw = dv * dv;

    const float4* xv = (const float4*)(x + (size_t)v * F);
    float4 a = xv[lane];
    float4 acc = make_float4(a.x * selfw, a.y * selfw, a.z * selfw, a.w * selfw);

    int i = beg;
    for (; i + UNROLL <= end; i += UNROLL) {
        int   s[UNROLL];
        float w[UNROLL];
        #pragma unroll
        for (int u = 0; u < UNROLL; ++u) { s[u] = csr_src[i + u]; w[u] = csr_w[i + u]; }
        float4 g[UNROLL];
        #pragma unroll
        for (int u = 0; u < UNROLL; ++u)
            g[u] = ((const float4*)(x + (size_t)s[u] * F))[lane];
        #pragma unroll
        for (int u = 0; u < UNROLL; ++u) {
            acc.x += g[u].x * w[u]; acc.y += g[u].y * w[u];
            acc.z += g[u].z * w[u]; acc.w += g[u].w * w[u];
        }
    }
    for (; i + 2 <= end; i += 2) {
        int s0 = csr_src[i], s1 = csr_src[i + 1];
        float w0 = csr_w[i], w1 = csr_w[i + 1];
        float4 x0 = ((const float4*)(x + (size_t)s0 * F))[lane];
        float4 x1 = ((const float4*)(x + (size_t)s1 * F))[lane];
        acc.x += x0.x * w0 + x1.x * w1; acc.y += x0.y * w0 + x1.y * w1;
        acc.z += x0.z * w0 + x1.z * w1; acc.w += x0.w * w0 + x1.w * w1;
    }
    if (i < end) {
        int s0 = csr_src[i];
        float w0 = csr_w[i];
        float4 x0 = ((const float4*)(x + (size_t)s0 * F))[lane];
        acc.x += x0.x * w0; acc.y += x0.y * w0; acc.z += x0.z * w0; acc.w += x0.w * w0;
    }

    ushort4 h, l;
    split2(acc.x, h.x, l.x);
    split2(acc.y, h.y, l.y);
    split2(acc.z, h.z, l.z);
    split2(acc.w, h.w, l.w);
    *(ushort4*)(yhi + (size_t)v * F + lane * 4) = h;
    *(ushort4*)(ylo + (size_t)v * F + lane * 4) = l;
}

// ---------------- gate: wgate[n] = sigmoid(x[n,:512] . pw + pb) ----------------
__global__ __launch_bounds__(256) void gate(const float* __restrict__ x, const float* __restrict__ pw,
                                            const float* __restrict__ pb, float* __restrict__ wgate, int n) {
    int wid = (blockIdx.x * 256 + threadIdx.x) >> 6;
    int lane = threadIdx.x & 63;
    if (wid >= n) return;
    const float4* xr = (const float4*)(x + (size_t)wid * 512);
    const float4* pwv = (const float4*)pw;
    float4 a = xr[lane], b = pwv[lane];
    float4 a1 = xr[lane + 64], b1 = pwv[lane + 64];
    float acc = a.x * b.x + a.y * b.y + a.z * b.z + a.w * b.w
              + a1.x * b1.x + a1.y * b1.y + a1.z * b1.z + a1.w * b1.w;
    #pragma unroll
    for (int off = 32; off; off >>= 1) acc += __shfl_down(acc, off, 64);
    if (lane == 0) wgate[wid] = 1.f / (1.f + expf(-(acc + pb[0])));
}

// ---------------- pool: pooled[g] = [weighted_sum(512) | max(512)] ----------------
__global__ __launch_bounds__(256) void pool(const float* __restrict__ x, const float* __restrict__ wg,
                                            const int* __restrict__ batch, float* __restrict__ pooled, int n) {
    int g = blockIdx.x;
    int t = threadIdx.x;
    int lo = 0, hi = n;
    while (lo < hi) { int mid = (lo + hi) >> 1; if (batch[mid] < g) lo = mid + 1; else hi = mid; }
    int start = lo;
    hi = n;
    while (lo < hi) { int mid = (lo + hi) >> 1; if (batch[mid] < g + 1) lo = mid + 1; else hi = mid; }
    int end = lo;
    float s0 = 0.f, s1 = 0.f, m0 = -INFINITY, m1 = -INFINITY;
    for (int nn = start; nn < end; ++nn) {
        float wn = wg[nn];
        const float* xr = x + (size_t)nn * 512;
        float v0 = xr[t], v1 = xr[t + 256];
        s0 += v0 * wn; s1 += v1 * wn;
        m0 = fmaxf(m0, v0); m1 = fmaxf(m1, v1);
    }
    if (start >= end) { m0 = 0.f; m1 = 0.f; }
    float* pg = pooled + (size_t)g * 1024;
    pg[t] = s0; pg[t + 256] = s1;
    pg[512 + t] = m0; pg[768 + t] = m1;
}

// ---------------- launch ----------------

extern "C" void kernel_launch(void* const* d_in, const int* in_sizes, int n_in,
                              void* d_out, int out_size, void* d_ws, size_t ws_size,
                              hipStream_t stream) {
    const float* x0    = (const float*)d_in[0];
    const int*   ei    = (const int*)d_in[1];
    const int*   batch = (const int*)d_in[2];
    const float* W1 = (const float*)d_in[3];
    const float* b1 = (const float*)d_in[4];
    const float* W2 = (const float*)d_in[5];
    const float* b2 = (const float*)d_in[6];
    const float* W3 = (const float*)d_in[7];
    const float* b3 = (const float*)d_in[8];
    const float* pw = (const float*)d_in[9];
    const float* pb = (const float*)d_in[10];
    const float* Wo = (const float*)d_in[11];
    const float* bo = (const float*)d_in[12];
    float* out = (float*)d_out;

    // workspace layout (float units, 16B-aligned regions)
    float* ws = (float*)d_ws;
    size_t off = 0;
    float* bufB = ws + off; off += (size_t)NNODES * 512;                 // layer outputs fp32
    ushort* yhi = (ushort*)(ws + off); off += (size_t)NNODES * 256 / 2;  // agg out hi
    ushort* ylo = (ushort*)(ws + off); off += (size_t)NNODES * 256 / 2;  // agg out lo
    ushort* W1thi = (ushort*)(ws + off); off += 256 * 256 / 2;
    ushort* W1tlo = (ushort*)(ws + off); off += 256 * 256 / 2;
    ushort* W2thi = (ushort*)(ws + off); off += 256 * 256 / 2;
    ushort* W2tlo = (ushort*)(ws + off); off += 256 * 256 / 2;
    ushort* W3thi = (ushort*)(ws + off); off += 512 * 256 / 2;
    ushort* W3tlo = (ushort*)(ws + off); off += 512 * 256 / 2;
    float* dis  = ws + off; off += NNODES;
    int*   degi = (int*)(ws + off); off += NNODES;
    int*   offs = (int*)(ws + off); off += (NNODES + 4);
    int*   curs = (int*)(ws + off); off += NNODES;
    int*   csr_src = (int*)(ws + off); off += NEDGES;
    float* csr_w   = ws + off; off += NEDGES;
    float* wgate   = ws + off; off += NNODES;
    float* pooled  = ws + off; off += (size_t)NGRAPH * 1024;
    int*   partials = (int*)(ws + off); off += 256;

    const int NB_N = (NNODES + 255) / 256;   // 196
    const int NB_E = (NEDGES + 255) / 256;
    const int NB_W = (NNODES + 3) / 4;       // wave per node (12500)
    const int MB128 = (NNODES + 127) / 128;  // 391

    // weight transpose+split (tiny)
    wsplit<<<(256 * 256 + 255) / 256, 256, 0, stream>>>(W1, W1thi, W1tlo, 256, 256);
    wsplit<<<(256 * 256 + 255) / 256, 256, 0, stream>>>(W2, W2thi, W2tlo, 256, 256);
    wsplit<<<(512 * 256 + 255) / 256, 256, 0, stream>>>(W3, W3thi, W3tlo, 256, 512);

    // CSR build
    zero_i32<<<NB_N, 256, 0, stream>>>(degi, NNODES);
    count_deg<<<NB_E, 256, 0, stream>>>(ei, degi, NEDGES);
    calc_dis<<<NB_N, 256, 0, stream>>>(degi, dis, NNODES);
    scanA<<<NB_N, 256, 0, stream>>>(degi, offs, partials, NNODES);
    scanB<<<1, 256, 0, stream>>>(partials, NB_N);
    scanC<<<NB_N, 256, 0, stream>>>(offs, partials, NNODES);
    copy_i32<<<NB_N, 256, 0, stream>>>(offs, curs, NNODES);
    fill_csr<<<NB_E, 256, 0, stream>>>(ei, dis, curs, csr_src, csr_w, NEDGES);

    // layer 1: y = A_norm @ x0 (bf16 hi/lo) ; x1 = relu(y @ W1 + b1) via MFMA
    agg256hl<<<NB_W, 256, 0, stream>>>(x0, yhi, ylo, dis, offs, csr_src, csr_w);
    {
        dim3 grid(H1 / 128, MB128);
        gemm_hl<<<grid, 256, 0, stream>>>(yhi, ylo, W1thi, W1tlo, bufB, b1, NNODES, H1, FIN, 1);
    }
    // layer 2
    agg256hl<<<NB_W, 256, 0, stream>>>(bufB, yhi, ylo, dis, offs, csr_src, csr_w);
    {
        dim3 grid(H2 / 128, MB128);
        gemm_hl<<<grid, 256, 0, stream>>>(yhi, ylo, W2thi, W2tlo, bufB, b2, NNODES, H2, H1, 1);
    }
    // layer 3: agg on 256-wide x2, MFMA GEMM 256->512
    agg256hl<<<NB_W, 256, 0, stream>>>(bufB, yhi, ylo, dis, offs, csr_src, csr_w);
    {
        dim3 grid(H3 / 128, MB128);
        gemm_hl<<<grid, 256, 0, stream>>>(yhi, ylo, W3thi, W3tlo, bufB, b3, NNODES, H3, H2, 1);
    }
    // gate + pool
    gate<<<(NNODES * 64 + 255) / 256, 256, 0, stream>>>(bufB, pw, pb, wgate, NNODES);
    pool<<<NGRAPH, 256, 0, stream>>>(bufB, wgate, batch, pooled, NNODES);
    // head: out = relu(pooled @ Wo + bo)  (small M -> fp32 64x64 sgemm)
    {
        dim3 grid(FPOUT / 64, NGRAPH / 64);
        sgemm<<<grid, 256, 0, stream>>>(pooled, Wo, out, bo, NGRAPH, FPOUT, 2 * H3, 1);
    }
}